// Round 1
// baseline (1171.629 us; speedup 1.0000x reference)
//
#include <hip/hip_runtime.h>
#include <math.h>

// LSTMClassifier fused kernel for MI355X (gfx950)
// B=1024, S=512, I=50, H=64, F1=32, C=2
// One block = 4 batch elements, 256 threads; thread u owns gate-unit jg=u
// (weights row in registers), and elementwise update for (b=u>>6, j=u&63).

#define B_TOT 1024
#define S_LEN 512
#define I_DIM 50
#define H_DIM 64
#define G4    256          // 4*H
#define KTOT  114          // I_DIM + H_DIM
#define BB    4            // batch per block
#define F1_DIM 32
#define C_DIM  2

__device__ __forceinline__ float fast_rcp(float x) {
    return __builtin_amdgcn_rcpf(x);
}
__device__ __forceinline__ float sigm(float v) {
    return fast_rcp(1.0f + __expf(-v));
}
__device__ __forceinline__ float tanh_fast(float v) {
    // tanh(x) = 1 - 2/(e^{2x}+1); saturates correctly for large |x|
    return 1.0f - 2.0f * fast_rcp(__expf(2.0f * v) + 1.0f);
}

__global__ __launch_bounds__(256, 1)
void lstm_fused(const float* __restrict__ x,
                const float* __restrict__ W_ih, const float* __restrict__ W_hh,
                const float* __restrict__ b_ih, const float* __restrict__ b_hh,
                const float* __restrict__ W1,  const float* __restrict__ b1,
                const float* __restrict__ W2,  const float* __restrict__ b2,
                float* __restrict__ out)
{
    __shared__ float act[2][KTOT][BB];     // [k][b]; k<50: x(t); k>=50: h(t)
    __shared__ float gbuf[4][BB][H_DIM];   // [gate][b][j] pre-activations
    __shared__ float f1buf[BB][F1_DIM];

    const int u  = threadIdx.x;            // 0..255
    const int jg = u;                      // owned gate-unit (row of W_ih/W_hh)
    const int b0 = blockIdx.x * BB;        // global batch base

    // ---- load this thread's weight row into registers (one-time, L2-hot) ----
    float w[KTOT];
    #pragma unroll
    for (int k = 0; k < I_DIM; ++k) w[k] = W_ih[jg * I_DIM + k];
    #pragma unroll
    for (int k = 0; k < H_DIM; ++k) w[I_DIM + k] = W_hh[jg * H_DIM + k];
    const float bias = b_ih[jg] + b_hh[jg];

    // elementwise role: one (b, j) cell per thread
    const int eb = u >> 6;                 // 0..3
    const int ej = u & 63;                 // 0..63
    float c_state = 0.0f;

    // x-prefetch role: 200 threads load 4 batches x 50 inputs
    const int pb = u / I_DIM;              // valid for u < 200
    const int pi = u - pb * I_DIM;

    // ---- init: stage x(t=0), zero h(0) ----
    if (u < BB * I_DIM) {
        act[0][pi][pb] = x[(size_t)(b0 + pb) * (S_LEN * I_DIM) + pi];
    }
    act[0][I_DIM + ej][eb] = 0.0f;         // h0 = 0 (covers all [4][64] cells)
    __syncthreads();

    // ---- sequential scan over time ----
    for (int t = 0; t < S_LEN; ++t) {
        const int cur = t & 1, nxt = cur ^ 1;

        // prefetch x(t+1) into registers (latency hidden under GEMM)
        float xpre = 0.0f;
        const bool do_pref = (t + 1 < S_LEN) && (u < BB * I_DIM);
        if (do_pref) {
            xpre = x[(size_t)(b0 + pb) * (S_LEN * I_DIM) + (t + 1) * I_DIM + pi];
        }

        // gate GEMM: acc[b] = bias + sum_k w[k] * act[k][b]
        float a0 = bias, a1 = bias, a2 = bias, a3 = bias;
        #pragma unroll
        for (int k = 0; k < KTOT; ++k) {
            const float4 av = *reinterpret_cast<const float4*>(&act[cur][k][0]);
            a0 = fmaf(w[k], av.x, a0);
            a1 = fmaf(w[k], av.y, a1);
            a2 = fmaf(w[k], av.z, a2);
            a3 = fmaf(w[k], av.w, a3);
        }
        const int g = jg >> 6, jj = jg & 63;
        gbuf[g][0][jj] = a0;
        gbuf[g][1][jj] = a1;
        gbuf[g][2][jj] = a2;
        gbuf[g][3][jj] = a3;
        __syncthreads();

        // elementwise LSTM cell for (eb, ej)
        const float gi = sigm(gbuf[0][eb][ej]);
        const float gf = sigm(gbuf[1][eb][ej]);
        const float gg = tanh_fast(gbuf[2][eb][ej]);
        const float go = sigm(gbuf[3][eb][ej]);
        c_state = gf * c_state + gi * gg;
        const float h_new = go * tanh_fast(c_state);
        act[nxt][I_DIM + ej][eb] = h_new;
        if (do_pref) act[nxt][pi][pb] = xpre;
        __syncthreads();
    }

    // ---- classifier head; h_last lives in act[0][50+j][b] (S_LEN even) ----
    if (u < BB * F1_DIM) {                 // 128 threads
        const int b = u >> 5, f = u & 31;
        float acc = b1[f];
        #pragma unroll
        for (int j = 0; j < H_DIM; ++j)
            acc = fmaf(act[0][I_DIM + j][b], W1[f * H_DIM + j], acc);
        f1buf[b][f] = fmaxf(acc, 0.0f);
    }
    __syncthreads();
    if (u < BB * C_DIM) {                  // 8 threads
        const int b = u >> 1, cl = u & 1;
        float acc = b2[cl];
        #pragma unroll
        for (int f = 0; f < F1_DIM; ++f)
            acc = fmaf(f1buf[b][f], W2[cl * F1_DIM + f], acc);
        out[(size_t)(b0 + b) * C_DIM + cl] = acc;
    }
}

extern "C" void kernel_launch(void* const* d_in, const int* in_sizes, int n_in,
                              void* d_out, int out_size, void* d_ws, size_t ws_size,
                              hipStream_t stream) {
    const float* x   = (const float*)d_in[0];
    const float* Wih = (const float*)d_in[1];
    const float* Whh = (const float*)d_in[2];
    const float* bih = (const float*)d_in[3];
    const float* bhh = (const float*)d_in[4];
    const float* W1  = (const float*)d_in[5];
    const float* b1  = (const float*)d_in[6];
    const float* W2  = (const float*)d_in[7];
    const float* b2  = (const float*)d_in[8];
    float* out = (float*)d_out;

    hipLaunchKernelGGL(lstm_fused, dim3(B_TOT / BB), dim3(256), 0, stream,
                       x, Wih, Whh, bih, bhh, W1, b1, W2, b2, out);
}

// Round 2
// 692.896 us; speedup vs baseline: 1.6909x; 1.6909x over previous
//
#include <hip/hip_runtime.h>
#include <math.h>

// LSTMClassifier fused kernel for MI355X (gfx950) — round 1: split-K 4-way
// B=1024, S=512, I=50, H=64, F1=32, C=2
// 1024 threads/block, 4 batch/block, grid=256 (1 block/CU).
// Thread u: gate-row jg=u&255, K-slice kp=u>>8 (29 of 116 padded K each).
// Weights (29 floats) live in registers; partials combined in elementwise phase.

#define B_TOT  1024
#define S_LEN  512
#define I_DIM  50
#define H_DIM  64
#define G4     256          // 4*H
#define KTOT   114          // I_DIM + H_DIM
#define KPAD   116          // padded to 4*29
#define KP     4            // K-slices
#define KPL    29           // K per slice
#define BB     4            // batch per block
#define F1_DIM 32
#define C_DIM  2

__device__ __forceinline__ float fast_rcp(float x) {
    return __builtin_amdgcn_rcpf(x);
}
__device__ __forceinline__ float sigm(float v) {
    return fast_rcp(1.0f + __expf(-v));
}
__device__ __forceinline__ float tanh_fast(float v) {
    // tanh(x) = 1 - 2/(e^{2x}+1); saturates correctly for large |x|
    return 1.0f - 2.0f * fast_rcp(__expf(2.0f * v) + 1.0f);
}

__global__ __launch_bounds__(1024, 4)
void lstm_fused(const float* __restrict__ x,
                const float* __restrict__ W_ih, const float* __restrict__ W_hh,
                const float* __restrict__ b_ih, const float* __restrict__ b_hh,
                const float* __restrict__ W1,  const float* __restrict__ b1,
                const float* __restrict__ W2,  const float* __restrict__ b2,
                float* __restrict__ out)
{
    __shared__ float act[2][KPAD][BB];       // [k][b]; k<50: x(t); 50..113: h(t); 114/115: 0-pad
    __shared__ float partial[KP][BB][G4];    // [kslice][b][gate_row]
    __shared__ float f1buf[BB][F1_DIM];

    const int u  = threadIdx.x;              // 0..1023
    const int jg = u & 255;                  // owned gate-row
    const int kp = u >> 8;                   // K-slice 0..3
    const int k0 = kp * KPL;
    const int b0 = blockIdx.x * BB;

    // ---- per-thread weight slice (29 floats) in registers ----
    float w[KPL];
    #pragma unroll
    for (int kk = 0; kk < KPL; ++kk) {
        const int k = k0 + kk;
        float v = 0.0f;
        if (k < I_DIM)      v = W_ih[jg * I_DIM + k];
        else if (k < KTOT)  v = W_hh[jg * H_DIM + (k - I_DIM)];
        w[kk] = v;
    }

    // elementwise role (threads 0..255): cell (eb, ej)
    const int eb = u >> 6;                   // valid for u<256: 0..3
    const int ej = u & 63;
    float bias4[4];
    #pragma unroll
    for (int g = 0; g < 4; ++g)
        bias4[g] = b_ih[g * H_DIM + ej] + b_hh[g * H_DIM + ej];
    float c_state = 0.0f;

    // x-prefetch role (threads 256..455): 4 batches x 50 inputs
    const int v256 = u - 256;
    const int pb = v256 / I_DIM;             // valid for 0 <= v256 < 200
    const int pi = v256 - pb * I_DIM;
    const bool is_pref = (v256 >= 0) && (v256 < BB * I_DIM);

    // ---- init: stage x(t=0), zero h(0), zero pad rows ----
    if (is_pref) {
        act[0][pi][pb] = x[(size_t)(b0 + pb) * (S_LEN * I_DIM) + pi];
    }
    if (u < 256) act[0][I_DIM + ej][eb] = 0.0f;      // h0 rows 50..113
    if (u < 16) {                                     // pad rows 114,115 both buffers
        act[u >> 3][KTOT + ((u >> 2) & 1)][u & 3] = 0.0f;
    }
    __syncthreads();

    // ---- sequential scan over time ----
    for (int t = 0; t < S_LEN; ++t) {
        const int cur = t & 1, nxt = cur ^ 1;

        // prefetch x(t+1) into registers (hidden under GEMM)
        float xpre = 0.0f;
        const bool do_pref = is_pref && (t + 1 < S_LEN);
        if (do_pref) {
            xpre = x[(size_t)(b0 + pb) * (S_LEN * I_DIM) + (t + 1) * I_DIM + pi];
        }

        // partial gate GEMM over this thread's K-slice
        float a0 = 0.0f, a1 = 0.0f, a2 = 0.0f, a3 = 0.0f;
        #pragma unroll
        for (int kk = 0; kk < KPL; ++kk) {
            const float4 av = *reinterpret_cast<const float4*>(&act[cur][k0 + kk][0]);
            a0 = fmaf(w[kk], av.x, a0);
            a1 = fmaf(w[kk], av.y, a1);
            a2 = fmaf(w[kk], av.z, a2);
            a3 = fmaf(w[kk], av.w, a3);
        }
        partial[kp][0][jg] = a0;    // lanes consecutive jg -> conflict-free
        partial[kp][1][jg] = a1;
        partial[kp][2][jg] = a2;
        partial[kp][3][jg] = a3;
        if (do_pref) act[nxt][pi][pb] = xpre;   // nxt buffer: safe before barrier
        __syncthreads();

        // elementwise LSTM cell (threads 0..255)
        if (u < 256) {
            float s[4];
            #pragma unroll
            for (int g = 0; g < 4; ++g) {
                float acc = bias4[g];
                #pragma unroll
                for (int p = 0; p < KP; ++p)
                    acc += partial[p][eb][g * H_DIM + ej];   // conflict-free
                s[g] = acc;
            }
            const float gi = sigm(s[0]);
            const float gf = sigm(s[1]);
            const float gg = tanh_fast(s[2]);
            const float go = sigm(s[3]);
            c_state = gf * c_state + gi * gg;
            act[nxt][I_DIM + ej][eb] = go * tanh_fast(c_state);
        }
        __syncthreads();
    }

    // ---- classifier head; h_last in act[0][50+j][b] (S_LEN even) ----
    if (u < BB * F1_DIM) {                   // 128 threads
        const int b = u >> 5, f = u & 31;
        float acc = b1[f];
        #pragma unroll
        for (int j = 0; j < H_DIM; ++j)
            acc = fmaf(act[0][I_DIM + j][b], W1[f * H_DIM + j], acc);
        f1buf[b][f] = fmaxf(acc, 0.0f);
    }
    __syncthreads();
    if (u < BB * C_DIM) {                    // 8 threads
        const int b = u >> 1, cl = u & 1;
        float acc = b2[cl];
        #pragma unroll
        for (int f = 0; f < F1_DIM; ++f)
            acc = fmaf(f1buf[b][f], W2[cl * F1_DIM + f], acc);
        out[(size_t)(b0 + b) * C_DIM + cl] = acc;
    }
}

extern "C" void kernel_launch(void* const* d_in, const int* in_sizes, int n_in,
                              void* d_out, int out_size, void* d_ws, size_t ws_size,
                              hipStream_t stream) {
    const float* x   = (const float*)d_in[0];
    const float* Wih = (const float*)d_in[1];
    const float* Whh = (const float*)d_in[2];
    const float* bih = (const float*)d_in[3];
    const float* bhh = (const float*)d_in[4];
    const float* W1  = (const float*)d_in[5];
    const float* b1  = (const float*)d_in[6];
    const float* W2  = (const float*)d_in[7];
    const float* b2  = (const float*)d_in[8];
    float* out = (float*)d_out;

    hipLaunchKernelGGL(lstm_fused, dim3(B_TOT / BB), dim3(1024), 0, stream,
                       x, Wih, Whh, bih, bhh, W1, b1, W2, b2, out);
}